// Round 7
// baseline (465.937 us; speedup 1.0000x reference)
//
#include <hip/hip_runtime.h>
#include <hip/hip_bf16.h>

// Problem constants (from reference)
#define N_NODES 100000
#define N_EDGES (N_NODES * 32)
#define BATCH   1024
#define SPAN    40000u
#define MULT    7296u    // 2^32 mod 40000
#define FILL_B  (N_EDGES / 256)   // 12500 blocks for fill

// CSR bucket-sort parameters (R15-proven geometry)
#define NB_BKT 391               // ceil(100000 / 256) buckets of 256 nodes
#define EPB    4096              // edges per block in bucket passes
#define SBLK   782               // ceil(N_EDGES / EPB)
#define BKT_CAP 8960             // fixed bucket capacity: mean 8192 + 8.5 sigma

// History: R4 882 -> R11 bucket-CSR 733.8 -> R12 float4-gather 549 ->
// R13 readlane-layer2 498.7 -> R15 fixed-cap buckets 462.9 -> R16 KG LDS
// staging 456.4us. R16 counters: k_layer2 53.8us top with VGPR_Count=44 --
// the 64-float weight arrays CANNOT fit 44 VGPRs => compiler spilled them
// to scratch under bare __launch_bounds__(256); every weight access is a
// scratch load (gemm/layer1 share the structure and the spill). R17:
// __launch_bounds__(256,4) (VGPR cap 128, weights register-resident) +
// two-node interleave so two independent FMA chains hide the 4-cy
// dependent latency. Per-node d=0..63 single-acc order unchanged =>
// bit-exact. All other kernels verbatim.

// ---------------- Threefry-2x32 (exact JAX schedule) ----------------
__host__ __device__ inline void threefry2x32(unsigned k0, unsigned k1,
                                             unsigned x0, unsigned x1,
                                             unsigned* o0, unsigned* o1)
{
  unsigned ks2 = k0 ^ k1 ^ 0x1BD11BDAu;
  unsigned v0 = x0 + k0, v1 = x1 + k1;
#define RL(x,d) (((x) << (d)) | ((x) >> (32 - (d))))
#define G4(a,b,c,dd) \
  v0 += v1; v1 = RL(v1,a);  v1 ^= v0; \
  v0 += v1; v1 = RL(v1,b);  v1 ^= v0; \
  v0 += v1; v1 = RL(v1,c);  v1 ^= v0; \
  v0 += v1; v1 = RL(v1,dd); v1 ^= v0;
  G4(13,15,26,6)  v0 += k1;  v1 += ks2 + 1u;
  G4(17,29,16,24) v0 += ks2; v1 += k0 + 2u;
  G4(13,15,26,6)  v0 += k0;  v1 += k1 + 3u;
  G4(17,29,16,24) v0 += k1;  v1 += ks2 + 4u;
  G4(13,15,26,6)  v0 += ks2; v1 += k0 + 5u;
#undef G4
#undef RL
  *o0 = v0; *o1 = v1;
}

__device__ __forceinline__ float bcastf(float v, int l)
{
  return __int_as_float(__builtin_amdgcn_readlane(__float_as_int(v), l));
}

// ================= bucket counting sort -> CSR =================

// R15 primary-path init: fixed-capacity bucket bases/cursors.
__global__ void k_init_buckets(int* __restrict__ bbase, int* __restrict__ bcur)
{
  int i = blockIdx.x * 256 + threadIdx.x;
  if (i < NB_BKT) { bbase[i] = i * BKT_CAP; bcur[i] = i * BKT_CAP; }
}

// Fallback pass A1: per-block LDS histogram over dst>>8 -> global bhist.
__global__ __launch_bounds__(256) void k_bucket_hist(
    const int* __restrict__ edge, int* __restrict__ bhist)
{
  __shared__ int h[NB_BKT];
  for (int i = threadIdx.x; i < NB_BKT; i += 256) h[i] = 0;
  __syncthreads();
  int base = blockIdx.x * EPB;
  int cnt = N_EDGES - base; if (cnt > EPB) cnt = EPB;
  const int4* e4 = (const int4*)(edge + base);
  int nq = cnt >> 2;
  for (int i = threadIdx.x; i < nq; i += 256) {
    int4 v = e4[i];
    atomicAdd(&h[v.x >> 8], 1); atomicAdd(&h[v.y >> 8], 1);
    atomicAdd(&h[v.z >> 8], 1); atomicAdd(&h[v.w >> 8], 1);
  }
  __syncthreads();
  for (int i = threadIdx.x; i < NB_BKT; i += 256)
    if (h[i]) atomicAdd(&bhist[i], h[i]);
}

// Fallback pass A2: exclusive scan of 391 bucket counts; init cursors.
__global__ void k_scan_buckets(const int* __restrict__ bhist,
                               int* __restrict__ bbase, int* __restrict__ bcur)
{
  __shared__ int s[512];
  int t = threadIdx.x;
  s[t] = (t < NB_BKT) ? bhist[t] : 0;
  __syncthreads();
  for (int o = 1; o < 512; o <<= 1) {
    int u = (t >= o) ? s[t - o] : 0;
    __syncthreads();
    s[t] += u;
    __syncthreads();
  }
  if (t < NB_BKT) {
    int excl = s[t] - bhist[t];
    bbase[t] = excl;
    bcur[t]  = excl;
  }
}

// Pass A3 (both paths): block counting-sorts its 4096 edges by bucket in
// LDS, reserves one contiguous run per bucket (1 atomicAdd on bcur, which
// already holds absolute offsets), copies runs out as PACKED 4B entries:
// (src_node << 8) | (dst & 255).  dst's high bits = bucket id.
__global__ __launch_bounds__(256) void k_bucket_scatter(
    const int* __restrict__ edge, int* __restrict__ bcur,
    int* __restrict__ pairs)
{
  __shared__ int  h[NB_BKT];
  __shared__ int  lbase[NB_BKT];
  __shared__ int  gbase[NB_BKT];
  __shared__ int  lcur[NB_BKT];
  __shared__ int2 buf[EPB];           // (dst, src) staging, 32 KB
  int t = threadIdx.x;
  for (int i = t; i < NB_BKT; i += 256) h[i] = 0;
  __syncthreads();
  int base = blockIdx.x * EPB;
  int cnt = N_EDGES - base; if (cnt > EPB) cnt = EPB;
  const int4* e4 = (const int4*)(edge + base);
  int nq = cnt >> 2;
  for (int i = t; i < nq; i += 256) {
    int4 v = e4[i];
    atomicAdd(&h[v.x >> 8], 1); atomicAdd(&h[v.y >> 8], 1);
    atomicAdd(&h[v.z >> 8], 1); atomicAdd(&h[v.w >> 8], 1);
  }
  __syncthreads();
  // exclusive scan of h -> lbase, by wave 0 in 64-wide chunks
  if (t < 64) {
    int run = 0;
    for (int c = 0; c < NB_BKT; c += 64) {
      int idx = c + t;
      int v = (idx < NB_BKT) ? h[idx] : 0;
      int orig = v;
      for (int o = 1; o < 64; o <<= 1) {
        int u = __shfl_up(v, o);
        if (t >= o) v += u;
      }
      if (idx < NB_BKT) lbase[idx] = run + v - orig;
      run += __shfl(v, 63);
    }
  }
  __syncthreads();
  for (int i = t; i < NB_BKT; i += 256) lcur[i] = lbase[i];
  __syncthreads();
  // place (dst, src_node) into buf grouped by bucket
  for (int i = t; i < nq; i += 256) {
    int4 v = e4[i];
    int eid = base + (i << 2);
    int p;
    p = atomicAdd(&lcur[v.x >> 8], 1); buf[p] = make_int2(v.x, (eid + 0) >> 5);
    p = atomicAdd(&lcur[v.y >> 8], 1); buf[p] = make_int2(v.y, (eid + 1) >> 5);
    p = atomicAdd(&lcur[v.z >> 8], 1); buf[p] = make_int2(v.z, (eid + 2) >> 5);
    p = atomicAdd(&lcur[v.w >> 8], 1); buf[p] = make_int2(v.w, (eid + 3) >> 5);
  }
  __syncthreads();
  // reserve global space per bucket (one atomic per non-empty bucket)
  for (int i = t; i < NB_BKT; i += 256) {
    int c = lcur[i] - lbase[i];
    gbase[i] = (c > 0) ? atomicAdd(&bcur[i], c) : 0;
  }
  __syncthreads();
  // copy runs out packed (consecutive i in same bucket -> consecutive pos)
  for (int i = t; i < cnt; i += 256) {
    int2 pr = buf[i];
    int b = pr.x >> 8;
    pairs[gbase[b] + (i - lbase[b])] = (pr.y << 8) | (pr.x & 255);
  }
}

// Pass B (both paths): one block per bucket (256 nodes). LDS per-node
// counters + scan -> final CSR (SRC NODE ids grouped per dst node),
// row_ptr (absolute), deg.  ecnt = bcur[b] - bbase[b].
__global__ __launch_bounds__(256) void k_bucket_csr(
    const int* __restrict__ bbase, const int* __restrict__ bcur,
    const int* __restrict__ pairs, int* __restrict__ csr,
    int* __restrict__ rowp, int* __restrict__ deg)
{
  __shared__ int nd[256], nb[256], nc[256];
  int b = blockIdx.x, t = threadIdx.x;
  int nb0 = b << 8;
  int ebase = bbase[b];
  int ecnt  = bcur[b] - ebase;
  nd[t] = 0; nc[t] = 0;
  __syncthreads();
  for (int i = t; i < ecnt; i += 256) {
    int pr = pairs[ebase + i];
    atomicAdd(&nd[pr & 255], 1);
  }
  __syncthreads();
  nb[t] = nd[t];
  __syncthreads();
  for (int o = 1; o < 256; o <<= 1) {
    int u = (t >= o) ? nb[t - o] : 0;
    __syncthreads();
    nb[t] += u;
    __syncthreads();
  }
  int excl = nb[t] - nd[t];
  int node = nb0 + t;
  if (node < N_NODES) { rowp[node] = ebase + excl; deg[node] = nd[t]; }
  __syncthreads();
  nb[t] = excl;
  __syncthreads();
  for (int i = t; i < ecnt; i += 256) {
    int pr = pairs[ebase + i];
    int l = pr & 255;
    int p = atomicAdd(&nc[l], 1);
    csr[ebase + nb[l] + p] = pr >> 8;    // src node id
  }
}

// float4 CSR gather: half-wave per node (R12-proven, unchanged).
__global__ __launch_bounds__(256) void k_gather_csr(
    const int* __restrict__ rowp, const int* __restrict__ deg,
    const int* __restrict__ csr, const float* __restrict__ src,
    float* __restrict__ out)
{
  int node = blockIdx.x * 8 + (threadIdx.x >> 5);
  int f = threadIdx.x & 31;
  int hb = threadIdx.x & 32;
  int sub = f >> 3;
  int q   = f & 7;
  int start = rowp[node];
  int dg = deg[node];
  const float4* src4 = (const float4*)src;
  float4 a0 = make_float4(0.f, 0.f, 0.f, 0.f);
  float4 a1 = make_float4(0.f, 0.f, 0.f, 0.f);
  for (int b0 = 0; b0 < dg; b0 += 32) {
    int idx = b0 + f;
    int e = (idx < dg) ? csr[start + idx] : -1;
#pragma unroll
    for (int j = 0; j < 8; j += 2) {
      int e0 = __shfl(e, hb + 4 * j + sub);
      int e1 = __shfl(e, hb + 4 * (j + 1) + sub);
      if (e0 >= 0) {
        float4 v = src4[(size_t)e0 * 8 + q];
        a0.x += v.x; a0.y += v.y; a0.z += v.z; a0.w += v.w;
      }
      if (e1 >= 0) {
        float4 v = src4[(size_t)e1 * 8 + q];
        a1.x += v.x; a1.y += v.y; a1.z += v.z; a1.w += v.w;
      }
    }
  }
  a0.x += a1.x; a0.y += a1.y; a0.z += a1.z; a0.w += a1.w;
  a0.x += __shfl_xor(a0.x, 8);  a0.y += __shfl_xor(a0.y, 8);
  a0.z += __shfl_xor(a0.z, 8);  a0.w += __shfl_xor(a0.w, 8);
  a0.x += __shfl_xor(a0.x, 16); a0.y += __shfl_xor(a0.y, 16);
  a0.z += __shfl_xor(a0.z, 16); a0.w += __shfl_xor(a0.w, 16);
  if (sub == 0) ((float4*)out)[(size_t)node * 8 + q] = a0;
}

// ---------------- legacy fused LL-fill + gemm (fallback paths) ----------
__global__ __launch_bounds__(256) void k_fill_gemm(
    const int* __restrict__ edge, int* __restrict__ head, int* __restrict__ next,
    int nsub, const float* __restrict__ x, const float* __restrict__ W,
    float* __restrict__ y)
{
  __shared__ float sw[32 * 65];
  if (blockIdx.x < FILL_B) {
    int e = blockIdx.x * 256 + threadIdx.x;
    int d = edge[e];
    int sub = e & (nsub - 1);
    int old = atomicExch(head + sub * N_NODES + d, e);
    next[e] = old;                       // coalesced by e
  } else {
    for (int t = threadIdx.x; t < 2048; t += 256) sw[(t >> 6) * 65 + (t & 63)] = W[t];
    __syncthreads();
    int i = (blockIdx.x - FILL_B) * 8 + (threadIdx.x >> 5);
    int f = threadIdx.x & 31;
    const float* xr = x + (size_t)i * 64;
    const float* wr = sw + f * 65;
    float acc = 0.f;
#pragma unroll
    for (int d = 0; d < 64; ++d) acc += xr[d] * wr[d];
    y[(size_t)i * 32 + f] = acc;
  }
}

// gather-aggregate via NSUB linked lists; half-wave (32 lanes) per node.
template<int NSUB>
__global__ __launch_bounds__(256) void k_gather_ll(
    const int* __restrict__ head, const int* __restrict__ next,
    const float* __restrict__ src, float* __restrict__ out,
    int* __restrict__ deg_out)
{
  int node = blockIdx.x * 8 + (threadIdx.x >> 5);
  int f = threadIdx.x & 31;
  int hb = threadIdx.x & 32;
  int e = (f < NSUB) ? head[f * N_NODES + node] : -1;
  float acc = 0.f;
  int cnt = 0;
  while (true) {
    int es[NSUB];
    bool any = false;
#pragma unroll
    for (int j = 0; j < NSUB; ++j) { es[j] = __shfl(e, hb + j); any |= (es[j] != -1); }
    if (!any) break;
    int en = -1;
    if (f < NSUB && e != -1) en = next[e];   // dependent chase load
#pragma unroll
    for (int j = 0; j < NSUB; ++j)
      if (es[j] != -1) { acc += src[(size_t)(es[j] >> 5) * 32 + f]; cnt++; }
    e = en;
  }
  out[(size_t)node * 32 + f] = acc;
  if (deg_out != nullptr && f == 0) deg_out[node] = cnt;
}

// ---------------- GCN dense kernels ----------------
// R17: __launch_bounds__(256,4) -> VGPR cap 128 so the weight arrays are
// REGISTER-resident (R16's VGPR_Count=44 proved they were scratch-spilled
// under bare launch_bounds(256)).  Two-node interleave: two independent
// FMA chains hide the 4-cy dependent latency.  Per-node d-order unchanged
// -> bit-exact.
#define DWB  3125   // 3125 x 4 waves x 8 nodes = 100000
#define DNPW 8

__global__ __launch_bounds__(256, 4) void k_gemm64x32(
    const float* __restrict__ x, const float* __restrict__ W, float* __restrict__ y)
{
  int lane = threadIdx.x & 63;
  int gw = blockIdx.x * 4 + (threadIdx.x >> 6);
  float wreg[64];
  const float* wrow = W + (size_t)(lane & 31) * 64;
#pragma unroll
  for (int d = 0; d < 64; ++d) wreg[d] = wrow[d];
  int n0 = gw * DNPW;
#pragma unroll 1
  for (int i = n0; i < n0 + DNPW; i += 2) {
    float v0 = x[(size_t)i * 64 + lane];
    float v1 = x[(size_t)(i + 1) * 64 + lane];
    float a0 = 0.f, a1 = 0.f;
#pragma unroll
    for (int d = 0; d < 64; ++d) {
      a0 += bcastf(v0, d) * wreg[d];
      a1 += bcastf(v1, d) * wreg[d];
    }
    if (lane < 32) {
      y[(size_t)i * 32 + lane]       = a0;
      y[(size_t)(i + 1) * 32 + lane] = a1;
    }
  }
}

__global__ __launch_bounds__(256) void k_scatter(
    const int* __restrict__ edge, const float* __restrict__ src,
    float* __restrict__ acc, int* __restrict__ cnt)
{
  int e = blockIdx.x * 8 + (threadIdx.x >> 5);
  int f = threadIdx.x & 31;
  int d = edge[e];
  atomicAdd(acc + (size_t)d * 32 + f, src[(size_t)(e >> 5) * 32 + f]);
  if (cnt != nullptr && f == 0) atomicAdd(cnt + d, 1);
}

__global__ __launch_bounds__(256, 4) void k_layer1(
    const float* __restrict__ sum1, const int* __restrict__ cnt,
    const float* __restrict__ x, const float* __restrict__ W1r,
    const float* __restrict__ b1, float* __restrict__ h)
{
  int lane = threadIdx.x & 63;
  int gw = blockIdx.x * 4 + (threadIdx.x >> 6);
  float wreg[64];
  const float* wrow = W1r + (size_t)(lane & 31) * 64;
#pragma unroll
  for (int d = 0; d < 64; ++d) wreg[d] = wrow[d];
  float sb = b1[lane & 31];
  int n0 = gw * DNPW;
#pragma unroll 1
  for (int i = n0; i < n0 + DNPW; i += 2) {
    float v0 = x[(size_t)i * 64 + lane];
    float v1 = x[(size_t)(i + 1) * 64 + lane];
    float a0 = 0.f, a1 = 0.f;
#pragma unroll
    for (int d = 0; d < 64; ++d) {
      a0 += bcastf(v0, d) * wreg[d];
      a1 += bcastf(v1, d) * wreg[d];
    }
    if (lane < 32) {
      float c0 = fmaxf((float)cnt[i], 1.f);
      float m0 = sum1[(size_t)i * 32 + lane] / c0;
      float r0 = (m0 + sb) + a0;
      h[(size_t)i * 32 + lane] = (r0 >= 0.f) ? r0 : 0.01f * r0;
      float c1 = fmaxf((float)cnt[i + 1], 1.f);
      float m1 = sum1[(size_t)(i + 1) * 32 + lane] / c1;
      float r1 = (m1 + sb) + a1;
      h[(size_t)(i + 1) * 32 + lane] = (r1 >= 0.f) ? r1 : 0.01f * r1;
    }
  }
}

#define L2_BLOCKS 3125
#define L2_NPW    8
__global__ __launch_bounds__(256, 4) void k_layer2(
    float* __restrict__ A, float* __restrict__ B, const int* __restrict__ cnt,
    const float* __restrict__ W2l, const float* __restrict__ W2r,
    const float* __restrict__ b2)
{
  int lane = threadIdx.x & 63;
  int gw = blockIdx.x * 4 + (threadIdx.x >> 6);
  float wl[32], wr[32];
#pragma unroll
  for (int f = 0; f < 32; ++f) { wl[f] = W2l[lane * 32 + f]; wr[f] = W2r[lane * 32 + f]; }
  float bb = b2[lane];
  int n0 = gw * L2_NPW;
#pragma unroll 1
  for (int i = n0; i < n0 + L2_NPW; i += 2) {
    float cA = fmaxf((float)cnt[i], 1.f);
    float cB = fmaxf((float)cnt[i + 1], 1.f);
    float vA, vB;
    if (lane < 32) {
      vA = B[(size_t)i * 32 + lane] / cA;
      vB = B[(size_t)(i + 1) * 32 + lane] / cB;
    } else {
      vA = A[(size_t)i * 32 + (lane - 32)];
      vB = A[(size_t)(i + 1) * 32 + (lane - 32)];
    }
    float accA = 0.f, acc2A = 0.f, accB = 0.f, acc2B = 0.f;
#pragma unroll
    for (int f = 0; f < 32; ++f) {
      accA  += bcastf(vA, f)      * wl[f];
      acc2A += bcastf(vA, 32 + f) * wr[f];
      accB  += bcastf(vB, f)      * wl[f];
      acc2B += bcastf(vB, 32 + f) * wr[f];
    }
    float tA = (accA + bb) + acc2A;
    float tB = (accB + bb) + acc2B;
    float sA = tA * tA, sB = tB * tB;
#pragma unroll
    for (int o = 32; o > 0; o >>= 1) {
      sA += __shfl_xor(sA, o);
      sB += __shfl_xor(sB, o);
    }
    float gA = tA / fmaxf(sqrtf(sA), 1e-12f);
    float gB = tB / fmaxf(sqrtf(sB), 1e-12f);
    if (lane < 32) {
      A[(size_t)i * 32 + lane]       = gA;
      A[(size_t)(i + 1) * 32 + lane] = gB;
    } else {
      B[(size_t)i * 32 + (lane - 32)]       = gA;
      B[(size_t)(i + 1) * 32 + (lane - 32)] = gB;
    }
  }
}

// ---------------- KG phase (R16-proven, verbatim) ----------------

__device__ inline float kg_score_lds(const float* __restrict__ row,
                                     const float* sp, const float* su)
{
  float acc = 0.f;
#pragma unroll
  for (int d = 0; d < 64; ++d) {
    float t = sp[d] * row[d];
    t = (t >= 0.f) ? t : 0.01f * t;
    acc += t * su[d];
  }
  return acc;
}

__device__ inline float wave_softmax(float acc)
{
  float m = acc;
#pragma unroll
  for (int o = 32; o > 0; o >>= 1) m = fmaxf(m, __shfl_xor(m, o));
  float e = expf(acc - m);
  float Z = e;
#pragma unroll
  for (int o = 32; o > 0; o >>= 1) Z += __shfl_xor(Z, o);
  return e / Z;
}

__device__ inline void load_row(const float* glo, const float* ghi, int node,
                                int lane, float* smem)
{
  smem[lane] = (lane < 32) ? glo[(size_t)node * 32 + lane]
                           : ghi[(size_t)node * 32 + (lane - 32)];
}

// stage 64 neighbor rows (nb per-lane) into sn[64][65], coalesced.
__device__ inline void stage_rows(const float* __restrict__ glo,
                                  const float* __restrict__ ghi,
                                  int nb, int lane, float* sn)
{
#pragma unroll
  for (int j = 0; j < 64; ++j) {
    int rj = __builtin_amdgcn_readlane(nb, j);
    float v = (lane < 32) ? glo[(size_t)rj * 32 + lane]
                          : ghi[(size_t)rj * 32 + (lane - 32)];
    sn[j * 65 + lane] = v;
  }
}

__global__ __launch_bounds__(64) void k_kg_argmax(
    const float* __restrict__ glo, const float* __restrict__ ghi,
    const int* __restrict__ users, const int* __restrict__ pvec,
    const int* __restrict__ adj, int* __restrict__ sel_out,
    float* __restrict__ logit_out)
{
  int b = blockIdx.x, lane = threadIdx.x;
  int u = users[b], pb = pvec[b];
  __shared__ float su[64], sp[64];
  __shared__ float sn[64 * 65];
  load_row(glo, ghi, u,  lane, su);
  load_row(glo, ghi, pb, lane, sp);
  int nb = adj[(size_t)pb * 64 + lane];
  stage_rows(glo, ghi, nb, lane, sn);
  __syncthreads();
  float sm = wave_softmax(kg_score_lds(sn + lane * 65, sp, su));
  float v = sm; int i = lane;
#pragma unroll
  for (int o = 32; o > 0; o >>= 1) {
    float ov = __shfl_xor(v, o); int oi = __shfl_xor(i, o);
    if (ov > v || (ov == v && oi < i)) { v = ov; i = oi; }
  }
  float smw = __shfl(sm, i);
  int sel = __shfl(nb, i);
  if (lane == 0) { sel_out[b] = sel; logit_out[b] = logf(smw); }
}

// R14-proven rank-based parallel top-32 (bit-identical to serial loop),
// with R16 LDS-staged rows.
__global__ __launch_bounds__(64) void k_kg_topk2(
    const float* __restrict__ glo, const float* __restrict__ ghi,
    const int* __restrict__ users, const int* __restrict__ srcA,
    const int* __restrict__ pvecB, const int* __restrict__ adj,
    unsigned a1a, unsigned a1b, unsigned a2a, unsigned a2b,
    unsigned c1a, unsigned c1b, unsigned c2a, unsigned c2b,
    int* __restrict__ candA, float* __restrict__ logA, int* __restrict__ candB)
{
  int b = blockIdx.x & (BATCH - 1);
  int var = blockIdx.x >> 10;
  int lane = threadIdx.x;
  int u = users[b];
  int pidx = (var == 0) ? srcA[b] : pvecB[b];
  int nbr  = (var == 0) ? srcA[b] : u;
  unsigned k1a = (var == 0) ? a1a : c1a, k1b = (var == 0) ? a1b : c1b;
  unsigned k2a = (var == 0) ? a2a : c2a, k2b = (var == 0) ? a2b : c2b;
  int* cand_out = (var == 0) ? candA : candB;
  float* logit_out = (var == 0) ? logA : nullptr;

  __shared__ float su[64], sp[64];
  __shared__ float sn[64 * 65];
  load_row(glo, ghi, u,    lane, su);
  load_row(glo, ghi, pidx, lane, sp);
  int nb = adj[(size_t)nbr * 64 + lane];
  stage_rows(glo, ghi, nb, lane, sn);
  __syncthreads();
  float sm = wave_softmax(kg_score_lds(sn + lane * 65, sp, su));
  int r = 0;
#pragma unroll
  for (int j = 0; j < 64; ++j) {
    float sj = bcastf(sm, j);
    if (sj > sm || (sj == sm && j < lane)) ++r;
  }
  if (r < 32) {
    int cand = nb;
    if (logit_out != nullptr) logit_out[b * 32 + r] = logf(sm);
    unsigned j = (unsigned)(b * 32 + r);
    unsigned h0, h1, l0, l1;
    threefry2x32(k1a, k1b, 0u, j, &h0, &h1);
    threefry2x32(k2a, k2b, 0u, j, &l0, &l1);
    unsigned hi = h0 ^ h1, lo = l0 ^ l1;
    unsigned rnd = ((hi % SPAN) * MULT + (lo % SPAN)) % SPAN;
    if (cand > 39999 || cand < 0) cand = (int)rnd;
    cand_out[b * 32 + r] = cand;
  }
}

// R16: prune with LDS-staged disc rows (dp rows j<32, dn rows j>=32).
__global__ __launch_bounds__(64) void k_kg_prune(
    const float* __restrict__ disc, const int* __restrict__ users,
    const int* __restrict__ cand, const float* __restrict__ two_log,
    const int* __restrict__ pos2, const float* __restrict__ one_log,
    float* __restrict__ out, int k, int* __restrict__ p_next)
{
  int b = blockIdx.x, lane = threadIdx.x;
  __shared__ float su[64];
  __shared__ float sd[64 * 65];
  su[lane] = disc[(size_t)users[b] * 64 + lane];
  int pr = (lane < 32) ? pos2[b * 32 + lane] : cand[b * 32 + (lane - 32)];
#pragma unroll
  for (int j = 0; j < 64; ++j) {
    int rj = __builtin_amdgcn_readlane(pr, j);
    sd[j * 65 + lane] = disc[(size_t)rj * 64 + lane];
  }
  __syncthreads();
  float r = 1e30f;
  if (lane < 32) {
    const float* dp = sd + lane * 65;
    const float* dn = sd + (32 + lane) * 65;
    float acc = 0.f;
#pragma unroll
    for (int d = 0; d < 64; ++d) acc += su[d] * (dp[d] - dn[d]);
    r = acc;
  }
  float v = r; int i = lane;
#pragma unroll
  for (int o = 32; o > 0; o >>= 1) {
    float ov = __shfl_xor(v, o); int oi = __shfl_xor(i, o);
    if (ov < v || (ov == v && oi < i)) { v = ov; i = oi; }
  }
  if (lane == 0) {
    int gn = cand[b * 32 + i];
    float gl = two_log[b * 32 + i] + one_log[b];
    out[k * BATCH + b]             = (float)gn;
    out[2 * BATCH + k * BATCH + b] = gl;
    p_next[b] = gn;
  }
}

// ---------------- launch ----------------
extern "C" void kernel_launch(void* const* d_in, const int* in_sizes, int n_in,
                              void* d_out, int out_size, void* d_ws, size_t ws_size,
                              hipStream_t stream)
{
  const float* x    = (const float*)d_in[0];
  const float* W1l  = (const float*)d_in[1];
  const float* W1r  = (const float*)d_in[2];
  const float* b1   = (const float*)d_in[3];
  const float* W2l  = (const float*)d_in[4];
  const float* W2r  = (const float*)d_in[5];
  const float* b2   = (const float*)d_in[6];
  const float* disc = (const float*)d_in[7];
  const int*   users= (const int*)d_in[8];
  const int*   pos  = (const int*)d_in[9];
  const int*   adj  = (const int*)d_in[10];
  const int*   edge = (const int*)d_in[11];
  float* out = (float*)d_out;

  char* w = (char*)d_ws;
  // R15 fixed-cap CSR layout (PAIRS_SZ = 391*8960*4 = 14,013,440):
  //   [0, 14,013,440)            csr (src ids grouped by dst, bucket gaps)
  //   [14,013,440, +400,000)     row_ptr (absolute)
  //   [14,413,440, +400,000)     deg
  //   [14,813,440, +2,048)       bbase
  //   [14,815,488, +2,048)       bcur
  //   [14,817,536, +14,013,440)  packed pairs — DEAD after k_bucket_csr;
  //                              A aliases pairs[0:12.8M)
  //   [28,830,976, +12,800,000)  B
  //   [41,630,976, +405,504)     KG buffers   => NEED_FIX = 42,036,480
  const size_t NEED_FIX = 42036480;
  const size_t NEED_CSR = 39617792;   // fallback: scan-based tight layout
  float *A, *B;
  char* bb;

  if (ws_size >= NEED_FIX) {
    int*  csr   = (int*)(w);
    int*  rowp  = (int*)(w + 14013440);
    int*  deg   = (int*)(w + 14413440);
    int*  bbase = (int*)(w + 14813440);
    int*  bcur  = (int*)(w + 14815488);
    int*  pairs = (int*)(w + 14817536);
    A = (float*)(w + 14817536);
    B = (float*)(w + 28830976);
    bb = w + 41630976;
    k_init_buckets<<<2, 256, 0, stream>>>(bbase, bcur);
    k_bucket_scatter<<<SBLK, 256, 0, stream>>>(edge, bcur, pairs);
    k_bucket_csr<<<NB_BKT, 256, 0, stream>>>(bbase, bcur, pairs, csr, rowp, deg);
    // pairs dead from here; gemm may now write A (aliases pairs)
    k_gemm64x32<<<DWB, 256, 0, stream>>>(x, W1l, A);
    k_gather_csr<<<N_NODES / 8, 256, 0, stream>>>(rowp, deg, csr, A, B);
    k_layer1<<<DWB, 256, 0, stream>>>(B, deg, x, W1r, b1, A);
    k_gather_csr<<<N_NODES / 8, 256, 0, stream>>>(rowp, deg, csr, A, B);
    k_layer2<<<L2_BLOCKS, 256, 0, stream>>>(A, B, deg, W2l, W2r, b2);
  } else if (ws_size >= NEED_CSR) {
    // fallback: R13-style scan-based tight CSR
    int*  csr   = (int*)(w);
    int*  rowp  = (int*)(w + 12800000);
    int*  deg   = (int*)(w + 13200000);
    int*  bhist = (int*)(w + 13600000);
    int*  bbase = (int*)(w + 13604096);
    int*  bcur  = (int*)(w + 13608192);
    int*  pairs = (int*)(w + 13612288);
    A = (float*)(w + 13612288);
    B = (float*)(w + 26412288);
    bb = w + 39212288;
    hipMemsetAsync(bhist, 0, 4096, stream);
    k_bucket_hist<<<SBLK, 256, 0, stream>>>(edge, bhist);
    k_scan_buckets<<<1, 512, 0, stream>>>(bhist, bbase, bcur);
    k_bucket_scatter<<<SBLK, 256, 0, stream>>>(edge, bcur, pairs);
    k_bucket_csr<<<NB_BKT, 256, 0, stream>>>(bbase, bcur, pairs, csr, rowp, deg);
    k_gemm64x32<<<DWB, 256, 0, stream>>>(x, W1l, A);
    k_gather_csr<<<N_NODES / 8, 256, 0, stream>>>(rowp, deg, csr, A, B);
    k_layer1<<<DWB, 256, 0, stream>>>(B, deg, x, W1r, b1, A);
    k_gather_csr<<<N_NODES / 8, 256, 0, stream>>>(rowp, deg, csr, A, B);
    k_layer2<<<L2_BLOCKS, 256, 0, stream>>>(A, B, deg, W2l, W2r, b2);
  } else {
    // fallback: proven atomic-scatter path (R4)
    int* cnt = (int*)w;
    A = (float*)(w + 409600);
    B = (float*)(w + 13209600);
    bb = w + 26009600;
    hipMemsetAsync(cnt, 0, 400000, stream);
    hipMemsetAsync(B, 0, 12800000, stream);
    k_gemm64x32<<<DWB, 256, 0, stream>>>(x, W1l, A);
    k_scatter<<<N_EDGES / 8, 256, 0, stream>>>(edge, A, B, cnt);
    k_layer1<<<DWB, 256, 0, stream>>>(B, cnt, x, W1r, b1, A);
    hipMemsetAsync(B, 0, 12800000, stream);
    k_scatter<<<N_EDGES / 8, 256, 0, stream>>>(edge, A, B, nullptr);
    k_layer2<<<L2_BLOCKS, 256, 0, stream>>>(A, B, cnt, W2l, W2r, b2);
  }

  int*   p_cur       = (int*)(bb);
  int*   one_hop_sel = (int*)(bb + 4096);
  float* one_hop_log = (float*)(bb + 8192);
  int*   cand        = (int*)(bb + 12288);
  float* two_log     = (float*)(bb + 143360);
  int*   pos2        = (int*)(bb + 274432);

  // --- KG walk, K_STEP = 2 (R7-proven dispatch structure) ---
  for (int k = 0; k < 2; ++k) {
    unsigned f0, f1, a1a, a1b, a2a, a2b, c1a, c1b, c2a, c2b;
    threefry2x32(0u, 123u, 0u, (unsigned)(2 * k), &f0, &f1);
    threefry2x32(f0, f1, 0u, 0u, &a1a, &a1b);
    threefry2x32(f0, f1, 0u, 1u, &a2a, &a2b);
    threefry2x32(0u, 123u, 0u, (unsigned)(2 * k + 1), &f0, &f1);
    threefry2x32(f0, f1, 0u, 0u, &c1a, &c1b);
    threefry2x32(f0, f1, 0u, 1u, &c2a, &c2b);

    const int* pvec = (k == 0) ? pos : p_cur;
    k_kg_argmax<<<BATCH, 64, 0, stream>>>(A, B, users, pvec, adj, one_hop_sel, one_hop_log);
    k_kg_topk2<<<2 * BATCH, 64, 0, stream>>>(A, B, users, one_hop_sel, pvec, adj,
                                             a1a, a1b, a2a, a2b, c1a, c1b, c2a, c2b,
                                             cand, two_log, pos2);
    k_kg_prune<<<BATCH, 64, 0, stream>>>(disc, users, cand, two_log, pos2,
                                         one_hop_log, out, k, p_cur);
  }
}

// Round 8
// 444.641 us; speedup vs baseline: 1.0479x; 1.0479x over previous
//
#include <hip/hip_runtime.h>
#include <hip/hip_bf16.h>

// Problem constants (from reference)
#define N_NODES 100000
#define N_EDGES (N_NODES * 32)
#define BATCH   1024
#define SPAN    40000u
#define MULT    7296u    // 2^32 mod 40000
#define FILL_B  (N_EDGES / 256)   // 12500 blocks for fill

// CSR bucket-sort parameters (R15-proven geometry)
#define NB_BKT 391               // ceil(100000 / 256) buckets of 256 nodes
#define EPB    4096              // edges per block in bucket passes
#define SBLK   782               // ceil(N_EDGES / EPB)
#define BKT_CAP 8960             // fixed bucket capacity: mean 8192 + 8.5 sigma

// History: R4 882 -> R11 bucket-CSR 733.8 -> R12 float4-gather 549 ->
// R13 readlane-layer2 498.7 -> R15 fixed-cap buckets 462.9 -> R16 KG LDS
// staging 456.4 -> R17 launch_bounds(256,4) 465.9 (FAILED: VGPR_Count=52,
// compiler still won't register-allocate the 64-float weight arrays;
// VALUBusy 49% = weight-reload + readlane hazard stalls). R18: TRANSPOSED
// dense kernels -- node-per-lane. Weights become wave-uniform (broadcast
// loads, zero per-lane weight regs -> spill problem structurally gone),
// no readlane, 32-64 independent acc chains, lane-local norm tree
// replicating the shfl_xor order exactly (asm barriers block FMA
// contraction of the squares). Per-output accumulation order, divisions,
// leaky, (accA+bb)+accB grouping all op-identical to R7 => bit-exact.
// Gather/buckets/KG verbatim.

// ---------------- Threefry-2x32 (exact JAX schedule) ----------------
__host__ __device__ inline void threefry2x32(unsigned k0, unsigned k1,
                                             unsigned x0, unsigned x1,
                                             unsigned* o0, unsigned* o1)
{
  unsigned ks2 = k0 ^ k1 ^ 0x1BD11BDAu;
  unsigned v0 = x0 + k0, v1 = x1 + k1;
#define RL(x,d) (((x) << (d)) | ((x) >> (32 - (d))))
#define G4(a,b,c,dd) \
  v0 += v1; v1 = RL(v1,a);  v1 ^= v0; \
  v0 += v1; v1 = RL(v1,b);  v1 ^= v0; \
  v0 += v1; v1 = RL(v1,c);  v1 ^= v0; \
  v0 += v1; v1 = RL(v1,dd); v1 ^= v0;
  G4(13,15,26,6)  v0 += k1;  v1 += ks2 + 1u;
  G4(17,29,16,24) v0 += ks2; v1 += k0 + 2u;
  G4(13,15,26,6)  v0 += k0;  v1 += k1 + 3u;
  G4(17,29,16,24) v0 += k1;  v1 += ks2 + 4u;
  G4(13,15,26,6)  v0 += ks2; v1 += k0 + 5u;
#undef G4
#undef RL
  *o0 = v0; *o1 = v1;
}

__device__ __forceinline__ float bcastf(float v, int l)
{
  return __int_as_float(__builtin_amdgcn_readlane(__float_as_int(v), l));
}

// opaque barrier: keeps a value as-is, blocks FMA contraction across it
__device__ __forceinline__ float fbar(float v)
{
  asm volatile("" : "+v"(v));
  return v;
}

// ================= bucket counting sort -> CSR =================

// R15 primary-path init: fixed-capacity bucket bases/cursors.
__global__ void k_init_buckets(int* __restrict__ bbase, int* __restrict__ bcur)
{
  int i = blockIdx.x * 256 + threadIdx.x;
  if (i < NB_BKT) { bbase[i] = i * BKT_CAP; bcur[i] = i * BKT_CAP; }
}

// Fallback pass A1: per-block LDS histogram over dst>>8 -> global bhist.
__global__ __launch_bounds__(256) void k_bucket_hist(
    const int* __restrict__ edge, int* __restrict__ bhist)
{
  __shared__ int h[NB_BKT];
  for (int i = threadIdx.x; i < NB_BKT; i += 256) h[i] = 0;
  __syncthreads();
  int base = blockIdx.x * EPB;
  int cnt = N_EDGES - base; if (cnt > EPB) cnt = EPB;
  const int4* e4 = (const int4*)(edge + base);
  int nq = cnt >> 2;
  for (int i = threadIdx.x; i < nq; i += 256) {
    int4 v = e4[i];
    atomicAdd(&h[v.x >> 8], 1); atomicAdd(&h[v.y >> 8], 1);
    atomicAdd(&h[v.z >> 8], 1); atomicAdd(&h[v.w >> 8], 1);
  }
  __syncthreads();
  for (int i = threadIdx.x; i < NB_BKT; i += 256)
    if (h[i]) atomicAdd(&bhist[i], h[i]);
}

// Fallback pass A2: exclusive scan of 391 bucket counts; init cursors.
__global__ void k_scan_buckets(const int* __restrict__ bhist,
                               int* __restrict__ bbase, int* __restrict__ bcur)
{
  __shared__ int s[512];
  int t = threadIdx.x;
  s[t] = (t < NB_BKT) ? bhist[t] : 0;
  __syncthreads();
  for (int o = 1; o < 512; o <<= 1) {
    int u = (t >= o) ? s[t - o] : 0;
    __syncthreads();
    s[t] += u;
    __syncthreads();
  }
  if (t < NB_BKT) {
    int excl = s[t] - bhist[t];
    bbase[t] = excl;
    bcur[t]  = excl;
  }
}

// Pass A3 (both paths): block counting-sorts its 4096 edges by bucket in
// LDS, reserves one contiguous run per bucket (1 atomicAdd on bcur, which
// already holds absolute offsets), copies runs out as PACKED 4B entries:
// (src_node << 8) | (dst & 255).  dst's high bits = bucket id.
__global__ __launch_bounds__(256) void k_bucket_scatter(
    const int* __restrict__ edge, int* __restrict__ bcur,
    int* __restrict__ pairs)
{
  __shared__ int  h[NB_BKT];
  __shared__ int  lbase[NB_BKT];
  __shared__ int  gbase[NB_BKT];
  __shared__ int  lcur[NB_BKT];
  __shared__ int2 buf[EPB];           // (dst, src) staging, 32 KB
  int t = threadIdx.x;
  for (int i = t; i < NB_BKT; i += 256) h[i] = 0;
  __syncthreads();
  int base = blockIdx.x * EPB;
  int cnt = N_EDGES - base; if (cnt > EPB) cnt = EPB;
  const int4* e4 = (const int4*)(edge + base);
  int nq = cnt >> 2;
  for (int i = t; i < nq; i += 256) {
    int4 v = e4[i];
    atomicAdd(&h[v.x >> 8], 1); atomicAdd(&h[v.y >> 8], 1);
    atomicAdd(&h[v.z >> 8], 1); atomicAdd(&h[v.w >> 8], 1);
  }
  __syncthreads();
  // exclusive scan of h -> lbase, by wave 0 in 64-wide chunks
  if (t < 64) {
    int run = 0;
    for (int c = 0; c < NB_BKT; c += 64) {
      int idx = c + t;
      int v = (idx < NB_BKT) ? h[idx] : 0;
      int orig = v;
      for (int o = 1; o < 64; o <<= 1) {
        int u = __shfl_up(v, o);
        if (t >= o) v += u;
      }
      if (idx < NB_BKT) lbase[idx] = run + v - orig;
      run += __shfl(v, 63);
    }
  }
  __syncthreads();
  for (int i = t; i < NB_BKT; i += 256) lcur[i] = lbase[i];
  __syncthreads();
  // place (dst, src_node) into buf grouped by bucket
  for (int i = t; i < nq; i += 256) {
    int4 v = e4[i];
    int eid = base + (i << 2);
    int p;
    p = atomicAdd(&lcur[v.x >> 8], 1); buf[p] = make_int2(v.x, (eid + 0) >> 5);
    p = atomicAdd(&lcur[v.y >> 8], 1); buf[p] = make_int2(v.y, (eid + 1) >> 5);
    p = atomicAdd(&lcur[v.z >> 8], 1); buf[p] = make_int2(v.z, (eid + 2) >> 5);
    p = atomicAdd(&lcur[v.w >> 8], 1); buf[p] = make_int2(v.w, (eid + 3) >> 5);
  }
  __syncthreads();
  // reserve global space per bucket (one atomic per non-empty bucket)
  for (int i = t; i < NB_BKT; i += 256) {
    int c = lcur[i] - lbase[i];
    gbase[i] = (c > 0) ? atomicAdd(&bcur[i], c) : 0;
  }
  __syncthreads();
  // copy runs out packed (consecutive i in same bucket -> consecutive pos)
  for (int i = t; i < cnt; i += 256) {
    int2 pr = buf[i];
    int b = pr.x >> 8;
    pairs[gbase[b] + (i - lbase[b])] = (pr.y << 8) | (pr.x & 255);
  }
}

// Pass B (both paths): one block per bucket (256 nodes). LDS per-node
// counters + scan -> final CSR (SRC NODE ids grouped per dst node),
// row_ptr (absolute), deg.  ecnt = bcur[b] - bbase[b].
__global__ __launch_bounds__(256) void k_bucket_csr(
    const int* __restrict__ bbase, const int* __restrict__ bcur,
    const int* __restrict__ pairs, int* __restrict__ csr,
    int* __restrict__ rowp, int* __restrict__ deg)
{
  __shared__ int nd[256], nb[256], nc[256];
  int b = blockIdx.x, t = threadIdx.x;
  int nb0 = b << 8;
  int ebase = bbase[b];
  int ecnt  = bcur[b] - ebase;
  nd[t] = 0; nc[t] = 0;
  __syncthreads();
  for (int i = t; i < ecnt; i += 256) {
    int pr = pairs[ebase + i];
    atomicAdd(&nd[pr & 255], 1);
  }
  __syncthreads();
  nb[t] = nd[t];
  __syncthreads();
  for (int o = 1; o < 256; o <<= 1) {
    int u = (t >= o) ? nb[t - o] : 0;
    __syncthreads();
    nb[t] += u;
    __syncthreads();
  }
  int excl = nb[t] - nd[t];
  int node = nb0 + t;
  if (node < N_NODES) { rowp[node] = ebase + excl; deg[node] = nd[t]; }
  __syncthreads();
  nb[t] = excl;
  __syncthreads();
  for (int i = t; i < ecnt; i += 256) {
    int pr = pairs[ebase + i];
    int l = pr & 255;
    int p = atomicAdd(&nc[l], 1);
    csr[ebase + nb[l] + p] = pr >> 8;    // src node id
  }
}

// float4 CSR gather: half-wave per node (R12-proven, unchanged).
__global__ __launch_bounds__(256) void k_gather_csr(
    const int* __restrict__ rowp, const int* __restrict__ deg,
    const int* __restrict__ csr, const float* __restrict__ src,
    float* __restrict__ out)
{
  int node = blockIdx.x * 8 + (threadIdx.x >> 5);
  int f = threadIdx.x & 31;
  int hb = threadIdx.x & 32;
  int sub = f >> 3;
  int q   = f & 7;
  int start = rowp[node];
  int dg = deg[node];
  const float4* src4 = (const float4*)src;
  float4 a0 = make_float4(0.f, 0.f, 0.f, 0.f);
  float4 a1 = make_float4(0.f, 0.f, 0.f, 0.f);
  for (int b0 = 0; b0 < dg; b0 += 32) {
    int idx = b0 + f;
    int e = (idx < dg) ? csr[start + idx] : -1;
#pragma unroll
    for (int j = 0; j < 8; j += 2) {
      int e0 = __shfl(e, hb + 4 * j + sub);
      int e1 = __shfl(e, hb + 4 * (j + 1) + sub);
      if (e0 >= 0) {
        float4 v = src4[(size_t)e0 * 8 + q];
        a0.x += v.x; a0.y += v.y; a0.z += v.z; a0.w += v.w;
      }
      if (e1 >= 0) {
        float4 v = src4[(size_t)e1 * 8 + q];
        a1.x += v.x; a1.y += v.y; a1.z += v.z; a1.w += v.w;
      }
    }
  }
  a0.x += a1.x; a0.y += a1.y; a0.z += a1.z; a0.w += a1.w;
  a0.x += __shfl_xor(a0.x, 8);  a0.y += __shfl_xor(a0.y, 8);
  a0.z += __shfl_xor(a0.z, 8);  a0.w += __shfl_xor(a0.w, 8);
  a0.x += __shfl_xor(a0.x, 16); a0.y += __shfl_xor(a0.y, 16);
  a0.z += __shfl_xor(a0.z, 16); a0.w += __shfl_xor(a0.w, 16);
  if (sub == 0) ((float4*)out)[(size_t)node * 8 + q] = a0;
}

// ---------------- legacy fused LL-fill + gemm (fallback paths) ----------
__global__ __launch_bounds__(256) void k_fill_gemm(
    const int* __restrict__ edge, int* __restrict__ head, int* __restrict__ next,
    int nsub, const float* __restrict__ x, const float* __restrict__ W,
    float* __restrict__ y)
{
  __shared__ float sw[32 * 65];
  if (blockIdx.x < FILL_B) {
    int e = blockIdx.x * 256 + threadIdx.x;
    int d = edge[e];
    int sub = e & (nsub - 1);
    int old = atomicExch(head + sub * N_NODES + d, e);
    next[e] = old;                       // coalesced by e
  } else {
    for (int t = threadIdx.x; t < 2048; t += 256) sw[(t >> 6) * 65 + (t & 63)] = W[t];
    __syncthreads();
    int i = (blockIdx.x - FILL_B) * 8 + (threadIdx.x >> 5);
    int f = threadIdx.x & 31;
    const float* xr = x + (size_t)i * 64;
    const float* wr = sw + f * 65;
    float acc = 0.f;
#pragma unroll
    for (int d = 0; d < 64; ++d) acc += xr[d] * wr[d];
    y[(size_t)i * 32 + f] = acc;
  }
}

// gather-aggregate via NSUB linked lists; half-wave (32 lanes) per node.
template<int NSUB>
__global__ __launch_bounds__(256) void k_gather_ll(
    const int* __restrict__ head, const int* __restrict__ next,
    const float* __restrict__ src, float* __restrict__ out,
    int* __restrict__ deg_out)
{
  int node = blockIdx.x * 8 + (threadIdx.x >> 5);
  int f = threadIdx.x & 31;
  int hb = threadIdx.x & 32;
  int e = (f < NSUB) ? head[f * N_NODES + node] : -1;
  float acc = 0.f;
  int cnt = 0;
  while (true) {
    int es[NSUB];
    bool any = false;
#pragma unroll
    for (int j = 0; j < NSUB; ++j) { es[j] = __shfl(e, hb + j); any |= (es[j] != -1); }
    if (!any) break;
    int en = -1;
    if (f < NSUB && e != -1) en = next[e];   // dependent chase load
#pragma unroll
    for (int j = 0; j < NSUB; ++j)
      if (es[j] != -1) { acc += src[(size_t)(es[j] >> 5) * 32 + f]; cnt++; }
    e = en;
  }
  out[(size_t)node * 32 + f] = acc;
  if (deg_out != nullptr && f == 0) deg_out[node] = cnt;
}

// ---------------- GCN dense kernels (R18: node-per-lane transposed) -----
// Lane l owns node wave*64+l. Weights are WAVE-UNIFORM (o unrolled) ->
// broadcast loads, zero per-lane weight registers (kills the R16/R17
// spill). Per-output accumulation: single ascending accumulator, order
// identical to the R7/R13 sequence -> bit-exact.
#define DGB 391   // 391 blocks x 4 waves x 64 nodes = 100,096 (tail guarded)

__global__ __launch_bounds__(256, 4) void k_gemm64x32(
    const float* __restrict__ x, const float* __restrict__ W, float* __restrict__ y)
{
  int lane = threadIdx.x & 63;
  int wv = blockIdx.x * 4 + (threadIdx.x >> 6);
  int node = wv * 64 + lane;
  bool ok = node < N_NODES;
  const float4* x4 = (const float4*)(x + (size_t)node * 64);
  const float4* W4 = (const float4*)W;
  float acc[32];
#pragma unroll
  for (int o = 0; o < 32; ++o) acc[o] = 0.f;
#pragma unroll 1
  for (int j = 0; j < 16; ++j) {
    float4 xv = ok ? x4[j] : make_float4(0.f, 0.f, 0.f, 0.f);
#pragma unroll
    for (int o = 0; o < 32; ++o) {
      float4 wv4 = W4[o * 16 + j];
      acc[o] += wv4.x * xv.x;
      acc[o] += wv4.y * xv.y;
      acc[o] += wv4.z * xv.z;
      acc[o] += wv4.w * xv.w;
    }
  }
  if (ok) {
    float4* y4 = (float4*)(y + (size_t)node * 32);
#pragma unroll
    for (int k = 0; k < 8; ++k)
      y4[k] = make_float4(acc[4 * k], acc[4 * k + 1], acc[4 * k + 2], acc[4 * k + 3]);
  }
}

__global__ __launch_bounds__(256) void k_scatter(
    const int* __restrict__ edge, const float* __restrict__ src,
    float* __restrict__ acc, int* __restrict__ cnt)
{
  int e = blockIdx.x * 8 + (threadIdx.x >> 5);
  int f = threadIdx.x & 31;
  int d = edge[e];
  atomicAdd(acc + (size_t)d * 32 + f, src[(size_t)(e >> 5) * 32 + f]);
  if (cnt != nullptr && f == 0) atomicAdd(cnt + d, 1);
}

__global__ __launch_bounds__(256, 4) void k_layer1(
    const float* __restrict__ sum1, const int* __restrict__ cnt,
    const float* __restrict__ x, const float* __restrict__ W1r,
    const float* __restrict__ b1, float* __restrict__ h)
{
  int lane = threadIdx.x & 63;
  int wv = blockIdx.x * 4 + (threadIdx.x >> 6);
  int node = wv * 64 + lane;
  bool ok = node < N_NODES;
  const float4* x4 = (const float4*)(x + (size_t)node * 64);
  const float4* W4 = (const float4*)W1r;
  float acc[32];
#pragma unroll
  for (int o = 0; o < 32; ++o) acc[o] = 0.f;
#pragma unroll 1
  for (int j = 0; j < 16; ++j) {
    float4 xv = ok ? x4[j] : make_float4(0.f, 0.f, 0.f, 0.f);
#pragma unroll
    for (int o = 0; o < 32; ++o) {
      float4 wv4 = W4[o * 16 + j];
      acc[o] += wv4.x * xv.x;
      acc[o] += wv4.y * xv.y;
      acc[o] += wv4.z * xv.z;
      acc[o] += wv4.w * xv.w;
    }
  }
  if (ok) {
    float c = fmaxf((float)cnt[node], 1.f);
    const float4* s4 = (const float4*)(sum1 + (size_t)node * 32);
    float4* h4 = (float4*)(h + (size_t)node * 32);
#pragma unroll
    for (int k = 0; k < 8; ++k) {
      float4 sv = s4[k];
      float4 r;
      // order per element: (mean + sb) + acc  (== R7/R13 sequence)
      r.x = ((sv.x / c) + b1[4 * k + 0]) + acc[4 * k + 0];
      r.y = ((sv.y / c) + b1[4 * k + 1]) + acc[4 * k + 1];
      r.z = ((sv.z / c) + b1[4 * k + 2]) + acc[4 * k + 2];
      r.w = ((sv.w / c) + b1[4 * k + 3]) + acc[4 * k + 3];
      r.x = (r.x >= 0.f) ? r.x : 0.01f * r.x;
      r.y = (r.y >= 0.f) ? r.y : 0.01f * r.y;
      r.z = (r.z >= 0.f) ? r.z : 0.01f * r.z;
      r.w = (r.w >= 0.f) ? r.w : 0.01f * r.w;
      h4[k] = r;
    }
  }
}

// layer2 transposed: two passes over output halves (regs: t_half[32] kept
// + accA[32]/accB[32] transient).  Per output o:
//   accA = sum_{f=0..31} W2l[o][f] * (B[n][f]/c)   (ascending, single acc)
//   tA   = accA + b2[o]
//   accB = sum_{f=0..31} W2r[o][f] * A[n][f]
//   t    = tA + accB                                (== (acc+bb)+acc2)
// Norm: explicit pairwise tree == shfl_xor(32,16,8,4,2,1) order; fbar()
// blocks FMA contraction of the squares (original had opaque shfl there).
__device__ __forceinline__ void l2_half(
    const float4* B4, const float4* A4, const float4* Wl4, const float4* Wr4,
    const float* b2, float c, bool ok, int obase, float* t)
{
  float accA[32];
#pragma unroll
  for (int o = 0; o < 32; ++o) accA[o] = 0.f;
#pragma unroll 1
  for (int j = 0; j < 8; ++j) {
    float4 bv = ok ? B4[j] : make_float4(0.f, 0.f, 0.f, 0.f);
    bv.x /= c; bv.y /= c; bv.z /= c; bv.w /= c;
#pragma unroll
    for (int o = 0; o < 32; ++o) {
      float4 w = Wl4[(obase + o) * 8 + j];
      accA[o] += w.x * bv.x;
      accA[o] += w.y * bv.y;
      accA[o] += w.z * bv.z;
      accA[o] += w.w * bv.w;
    }
  }
#pragma unroll
  for (int o = 0; o < 32; ++o) accA[o] = accA[o] + b2[obase + o];   // tA
  float accB[32];
#pragma unroll
  for (int o = 0; o < 32; ++o) accB[o] = 0.f;
#pragma unroll 1
  for (int j = 0; j < 8; ++j) {
    float4 av = ok ? A4[j] : make_float4(0.f, 0.f, 0.f, 0.f);
#pragma unroll
    for (int o = 0; o < 32; ++o) {
      float4 w = Wr4[(obase + o) * 8 + j];
      accB[o] += w.x * av.x;
      accB[o] += w.y * av.y;
      accB[o] += w.z * av.z;
      accB[o] += w.w * av.w;
    }
  }
#pragma unroll
  for (int o = 0; o < 32; ++o) t[o] = accA[o] + accB[o];
}

__global__ __launch_bounds__(256, 4) void k_layer2(
    float* __restrict__ A, float* __restrict__ B, const int* __restrict__ cnt,
    const float* __restrict__ W2l, const float* __restrict__ W2r,
    const float* __restrict__ b2)
{
  int lane = threadIdx.x & 63;
  int wv = blockIdx.x * 4 + (threadIdx.x >> 6);
  int node = wv * 64 + lane;
  bool ok = node < N_NODES;
  float c = 1.f;
  if (ok) c = fmaxf((float)cnt[node], 1.f);
  const float4* B4 = (const float4*)(B + (size_t)node * 32);
  const float4* A4 = (const float4*)(A + (size_t)node * 32);
  const float4* Wl4 = (const float4*)W2l;
  const float4* Wr4 = (const float4*)W2r;
  float t0[32], t1[32];
  l2_half(B4, A4, Wl4, Wr4, b2, c, ok, 0,  t0);
  l2_half(B4, A4, Wl4, Wr4, b2, c, ok, 32, t1);
  // norm tree (== shfl_xor order 32,16,8,4,2,1)
  float a[32];
#pragma unroll
  for (int k = 0; k < 32; ++k) {
    float v0 = fbar(t0[k] * t0[k]);
    float v1 = fbar(t1[k] * t1[k]);
    a[k] = v0 + v1;
  }
  float bv[16];
#pragma unroll
  for (int k = 0; k < 16; ++k) bv[k] = a[k] + a[k + 16];
  float cv[8];
#pragma unroll
  for (int k = 0; k < 8; ++k) cv[k] = bv[k] + bv[k + 8];
  float dv[4];
#pragma unroll
  for (int k = 0; k < 4; ++k) dv[k] = cv[k] + cv[k + 4];
  float ev0 = dv[0] + dv[2], ev1 = dv[1] + dv[3];
  float s = (ev0 + ev1);
  // careful: order of last two levels: offset2 then offset1:
  //   e_k = d_k + d_{k+2} (k<2); s = e_0 + e_1
  // (computed above as ev0 = d0+d2, ev1 = d1+d3, s = ev0+ev1)
  float den = fmaxf(sqrtf(s), 1e-12f);
  if (ok) {
    float4* Ao = (float4*)(A + (size_t)node * 32);
    float4* Bo = (float4*)(B + (size_t)node * 32);
#pragma unroll
    for (int k = 0; k < 8; ++k) {
      Ao[k] = make_float4(t0[4 * k] / den, t0[4 * k + 1] / den,
                          t0[4 * k + 2] / den, t0[4 * k + 3] / den);
      Bo[k] = make_float4(t1[4 * k] / den, t1[4 * k + 1] / den,
                          t1[4 * k + 2] / den, t1[4 * k + 3] / den);
    }
  }
}

// ---------------- KG phase (R16-proven, verbatim) ----------------

__device__ inline float kg_score_lds(const float* __restrict__ row,
                                     const float* sp, const float* su)
{
  float acc = 0.f;
#pragma unroll
  for (int d = 0; d < 64; ++d) {
    float t = sp[d] * row[d];
    t = (t >= 0.f) ? t : 0.01f * t;
    acc += t * su[d];
  }
  return acc;
}

__device__ inline float wave_softmax(float acc)
{
  float m = acc;
#pragma unroll
  for (int o = 32; o > 0; o >>= 1) m = fmaxf(m, __shfl_xor(m, o));
  float e = expf(acc - m);
  float Z = e;
#pragma unroll
  for (int o = 32; o > 0; o >>= 1) Z += __shfl_xor(Z, o);
  return e / Z;
}

__device__ inline void load_row(const float* glo, const float* ghi, int node,
                                int lane, float* smem)
{
  smem[lane] = (lane < 32) ? glo[(size_t)node * 32 + lane]
                           : ghi[(size_t)node * 32 + (lane - 32)];
}

// stage 64 neighbor rows (nb per-lane) into sn[64][65], coalesced.
__device__ inline void stage_rows(const float* __restrict__ glo,
                                  const float* __restrict__ ghi,
                                  int nb, int lane, float* sn)
{
#pragma unroll
  for (int j = 0; j < 64; ++j) {
    int rj = __builtin_amdgcn_readlane(nb, j);
    float v = (lane < 32) ? glo[(size_t)rj * 32 + lane]
                          : ghi[(size_t)rj * 32 + (lane - 32)];
    sn[j * 65 + lane] = v;
  }
}

__global__ __launch_bounds__(64) void k_kg_argmax(
    const float* __restrict__ glo, const float* __restrict__ ghi,
    const int* __restrict__ users, const int* __restrict__ pvec,
    const int* __restrict__ adj, int* __restrict__ sel_out,
    float* __restrict__ logit_out)
{
  int b = blockIdx.x, lane = threadIdx.x;
  int u = users[b], pb = pvec[b];
  __shared__ float su[64], sp[64];
  __shared__ float sn[64 * 65];
  load_row(glo, ghi, u,  lane, su);
  load_row(glo, ghi, pb, lane, sp);
  int nb = adj[(size_t)pb * 64 + lane];
  stage_rows(glo, ghi, nb, lane, sn);
  __syncthreads();
  float sm = wave_softmax(kg_score_lds(sn + lane * 65, sp, su));
  float v = sm; int i = lane;
#pragma unroll
  for (int o = 32; o > 0; o >>= 1) {
    float ov = __shfl_xor(v, o); int oi = __shfl_xor(i, o);
    if (ov > v || (ov == v && oi < i)) { v = ov; i = oi; }
  }
  float smw = __shfl(sm, i);
  int sel = __shfl(nb, i);
  if (lane == 0) { sel_out[b] = sel; logit_out[b] = logf(smw); }
}

// R14-proven rank-based parallel top-32 (bit-identical to serial loop),
// with R16 LDS-staged rows.
__global__ __launch_bounds__(64) void k_kg_topk2(
    const float* __restrict__ glo, const float* __restrict__ ghi,
    const int* __restrict__ users, const int* __restrict__ srcA,
    const int* __restrict__ pvecB, const int* __restrict__ adj,
    unsigned a1a, unsigned a1b, unsigned a2a, unsigned a2b,
    unsigned c1a, unsigned c1b, unsigned c2a, unsigned c2b,
    int* __restrict__ candA, float* __restrict__ logA, int* __restrict__ candB)
{
  int b = blockIdx.x & (BATCH - 1);
  int var = blockIdx.x >> 10;
  int lane = threadIdx.x;
  int u = users[b];
  int pidx = (var == 0) ? srcA[b] : pvecB[b];
  int nbr  = (var == 0) ? srcA[b] : u;
  unsigned k1a = (var == 0) ? a1a : c1a, k1b = (var == 0) ? a1b : c1b;
  unsigned k2a = (var == 0) ? a2a : c2a, k2b = (var == 0) ? a2b : c2b;
  int* cand_out = (var == 0) ? candA : candB;
  float* logit_out = (var == 0) ? logA : nullptr;

  __shared__ float su[64], sp[64];
  __shared__ float sn[64 * 65];
  load_row(glo, ghi, u,    lane, su);
  load_row(glo, ghi, pidx, lane, sp);
  int nb = adj[(size_t)nbr * 64 + lane];
  stage_rows(glo, ghi, nb, lane, sn);
  __syncthreads();
  float sm = wave_softmax(kg_score_lds(sn + lane * 65, sp, su));
  int r = 0;
#pragma unroll
  for (int j = 0; j < 64; ++j) {
    float sj = bcastf(sm, j);
    if (sj > sm || (sj == sm && j < lane)) ++r;
  }
  if (r < 32) {
    int cand = nb;
    if (logit_out != nullptr) logit_out[b * 32 + r] = logf(sm);
    unsigned j = (unsigned)(b * 32 + r);
    unsigned h0, h1, l0, l1;
    threefry2x32(k1a, k1b, 0u, j, &h0, &h1);
    threefry2x32(k2a, k2b, 0u, j, &l0, &l1);
    unsigned hi = h0 ^ h1, lo = l0 ^ l1;
    unsigned rnd = ((hi % SPAN) * MULT + (lo % SPAN)) % SPAN;
    if (cand > 39999 || cand < 0) cand = (int)rnd;
    cand_out[b * 32 + r] = cand;
  }
}

// R16: prune with LDS-staged disc rows (dp rows j<32, dn rows j>=32).
__global__ __launch_bounds__(64) void k_kg_prune(
    const float* __restrict__ disc, const int* __restrict__ users,
    const int* __restrict__ cand, const float* __restrict__ two_log,
    const int* __restrict__ pos2, const float* __restrict__ one_log,
    float* __restrict__ out, int k, int* __restrict__ p_next)
{
  int b = blockIdx.x, lane = threadIdx.x;
  __shared__ float su[64];
  __shared__ float sd[64 * 65];
  su[lane] = disc[(size_t)users[b] * 64 + lane];
  int pr = (lane < 32) ? pos2[b * 32 + lane] : cand[b * 32 + (lane - 32)];
#pragma unroll
  for (int j = 0; j < 64; ++j) {
    int rj = __builtin_amdgcn_readlane(pr, j);
    sd[j * 65 + lane] = disc[(size_t)rj * 64 + lane];
  }
  __syncthreads();
  float r = 1e30f;
  if (lane < 32) {
    const float* dp = sd + lane * 65;
    const float* dn = sd + (32 + lane) * 65;
    float acc = 0.f;
#pragma unroll
    for (int d = 0; d < 64; ++d) acc += su[d] * (dp[d] - dn[d]);
    r = acc;
  }
  float v = r; int i = lane;
#pragma unroll
  for (int o = 32; o > 0; o >>= 1) {
    float ov = __shfl_xor(v, o); int oi = __shfl_xor(i, o);
    if (ov < v || (ov == v && oi < i)) { v = ov; i = oi; }
  }
  if (lane == 0) {
    int gn = cand[b * 32 + i];
    float gl = two_log[b * 32 + i] + one_log[b];
    out[k * BATCH + b]             = (float)gn;
    out[2 * BATCH + k * BATCH + b] = gl;
    p_next[b] = gn;
  }
}

// ---------------- launch ----------------
extern "C" void kernel_launch(void* const* d_in, const int* in_sizes, int n_in,
                              void* d_out, int out_size, void* d_ws, size_t ws_size,
                              hipStream_t stream)
{
  const float* x    = (const float*)d_in[0];
  const float* W1l  = (const float*)d_in[1];
  const float* W1r  = (const float*)d_in[2];
  const float* b1   = (const float*)d_in[3];
  const float* W2l  = (const float*)d_in[4];
  const float* W2r  = (const float*)d_in[5];
  const float* b2   = (const float*)d_in[6];
  const float* disc = (const float*)d_in[7];
  const int*   users= (const int*)d_in[8];
  const int*   pos  = (const int*)d_in[9];
  const int*   adj  = (const int*)d_in[10];
  const int*   edge = (const int*)d_in[11];
  float* out = (float*)d_out;

  char* w = (char*)d_ws;
  // R15 fixed-cap CSR layout (PAIRS_SZ = 391*8960*4 = 14,013,440):
  //   [0, 14,013,440)            csr (src ids grouped by dst, bucket gaps)
  //   [14,013,440, +400,000)     row_ptr (absolute)
  //   [14,413,440, +400,000)     deg
  //   [14,813,440, +2,048)       bbase
  //   [14,815,488, +2,048)       bcur
  //   [14,817,536, +14,013,440)  packed pairs — DEAD after k_bucket_csr;
  //                              A aliases pairs[0:12.8M)
  //   [28,830,976, +12,800,000)  B
  //   [41,630,976, +405,504)     KG buffers   => NEED_FIX = 42,036,480
  const size_t NEED_FIX = 42036480;
  const size_t NEED_CSR = 39617792;   // fallback: scan-based tight layout
  float *A, *B;
  char* bb;

  if (ws_size >= NEED_FIX) {
    int*  csr   = (int*)(w);
    int*  rowp  = (int*)(w + 14013440);
    int*  deg   = (int*)(w + 14413440);
    int*  bbase = (int*)(w + 14813440);
    int*  bcur  = (int*)(w + 14815488);
    int*  pairs = (int*)(w + 14817536);
    A = (float*)(w + 14817536);
    B = (float*)(w + 28830976);
    bb = w + 41630976;
    k_init_buckets<<<2, 256, 0, stream>>>(bbase, bcur);
    k_bucket_scatter<<<SBLK, 256, 0, stream>>>(edge, bcur, pairs);
    k_bucket_csr<<<NB_BKT, 256, 0, stream>>>(bbase, bcur, pairs, csr, rowp, deg);
    // pairs dead from here; gemm may now write A (aliases pairs)
    k_gemm64x32<<<DGB, 256, 0, stream>>>(x, W1l, A);
    k_gather_csr<<<N_NODES / 8, 256, 0, stream>>>(rowp, deg, csr, A, B);
    k_layer1<<<DGB, 256, 0, stream>>>(B, deg, x, W1r, b1, A);
    k_gather_csr<<<N_NODES / 8, 256, 0, stream>>>(rowp, deg, csr, A, B);
    k_layer2<<<DGB, 256, 0, stream>>>(A, B, deg, W2l, W2r, b2);
  } else if (ws_size >= NEED_CSR) {
    // fallback: R13-style scan-based tight CSR
    int*  csr   = (int*)(w);
    int*  rowp  = (int*)(w + 12800000);
    int*  deg   = (int*)(w + 13200000);
    int*  bhist = (int*)(w + 13600000);
    int*  bbase = (int*)(w + 13604096);
    int*  bcur  = (int*)(w + 13608192);
    int*  pairs = (int*)(w + 13612288);
    A = (float*)(w + 13612288);
    B = (float*)(w + 26412288);
    bb = w + 39212288;
    hipMemsetAsync(bhist, 0, 4096, stream);
    k_bucket_hist<<<SBLK, 256, 0, stream>>>(edge, bhist);
    k_scan_buckets<<<1, 512, 0, stream>>>(bhist, bbase, bcur);
    k_bucket_scatter<<<SBLK, 256, 0, stream>>>(edge, bcur, pairs);
    k_bucket_csr<<<NB_BKT, 256, 0, stream>>>(bbase, bcur, pairs, csr, rowp, deg);
    k_gemm64x32<<<DGB, 256, 0, stream>>>(x, W1l, A);
    k_gather_csr<<<N_NODES / 8, 256, 0, stream>>>(rowp, deg, csr, A, B);
    k_layer1<<<DGB, 256, 0, stream>>>(B, deg, x, W1r, b1, A);
    k_gather_csr<<<N_NODES / 8, 256, 0, stream>>>(rowp, deg, csr, A, B);
    k_layer2<<<DGB, 256, 0, stream>>>(A, B, deg, W2l, W2r, b2);
  } else {
    // fallback: proven atomic-scatter path (R4)
    int* cnt = (int*)w;
    A = (float*)(w + 409600);
    B = (float*)(w + 13209600);
    bb = w + 26009600;
    hipMemsetAsync(cnt, 0, 400000, stream);
    hipMemsetAsync(B, 0, 12800000, stream);
    k_gemm64x32<<<DGB, 256, 0, stream>>>(x, W1l, A);
    k_scatter<<<N_EDGES / 8, 256, 0, stream>>>(edge, A, B, cnt);
    k_layer1<<<DGB, 256, 0, stream>>>(B, cnt, x, W1r, b1, A);
    hipMemsetAsync(B, 0, 12800000, stream);
    k_scatter<<<N_EDGES / 8, 256, 0, stream>>>(edge, A, B, nullptr);
    k_layer2<<<DGB, 256, 0, stream>>>(A, B, cnt, W2l, W2r, b2);
  }

  int*   p_cur       = (int*)(bb);
  int*   one_hop_sel = (int*)(bb + 4096);
  float* one_hop_log = (float*)(bb + 8192);
  int*   cand        = (int*)(bb + 12288);
  float* two_log     = (float*)(bb + 143360);
  int*   pos2        = (int*)(bb + 274432);

  // --- KG walk, K_STEP = 2 (R7-proven dispatch structure) ---
  for (int k = 0; k < 2; ++k) {
    unsigned f0, f1, a1a, a1b, a2a, a2b, c1a, c1b, c2a, c2b;
    threefry2x32(0u, 123u, 0u, (unsigned)(2 * k), &f0, &f1);
    threefry2x32(f0, f1, 0u, 0u, &a1a, &a1b);
    threefry2x32(f0, f1, 0u, 1u, &a2a, &a2b);
    threefry2x32(0u, 123u, 0u, (unsigned)(2 * k + 1), &f0, &f1);
    threefry2x32(f0, f1, 0u, 0u, &c1a, &c1b);
    threefry2x32(f0, f1, 0u, 1u, &c2a, &c2b);

    const int* pvec = (k == 0) ? pos : p_cur;
    k_kg_argmax<<<BATCH, 64, 0, stream>>>(A, B, users, pvec, adj, one_hop_sel, one_hop_log);
    k_kg_topk2<<<2 * BATCH, 64, 0, stream>>>(A, B, users, one_hop_sel, pvec, adj,
                                             a1a, a1b, a2a, a2b, c1a, c1b, c2a, c2b,
                                             cand, two_log, pos2);
    k_kg_prune<<<BATCH, 64, 0, stream>>>(disc, users, cand, two_log, pos2,
                                         one_hop_log, out, k, p_cur);
  }
}